// Round 1
// baseline (416.611 us; speedup 1.0000x reference)
//
#include <hip/hip_runtime.h>

#define DD 128
#define HH 64
#define RR 4
#define BM 64
#define NT 256

// ---------------- relation counting sort ----------------
__global__ void k_count(const int* __restrict__ et, int* __restrict__ cnt, int E) {
    __shared__ int h[RR];
    int t = threadIdx.x;
    if (t < RR) h[t] = 0;
    __syncthreads();
    int i = blockIdx.x * blockDim.x + t;
    if (i < E) atomicAdd(&h[et[i]], 1);
    __syncthreads();
    if (t < RR) atomicAdd(&cnt[t], h[t]);
}

__global__ void k_scan(const int* __restrict__ cnt, int* __restrict__ segStart,
                       int* __restrict__ cursor) {
    if (threadIdx.x == 0 && blockIdx.x == 0) {
        int s = 0;
        for (int r = 0; r < RR; r++) { segStart[r] = s; cursor[r] = s; s += cnt[r]; }
    }
}

__global__ void k_scatter(const int* __restrict__ et, int* __restrict__ cursor,
                          int* __restrict__ perm, int E) {
    __shared__ int h[RR];
    __shared__ int base[RR];
    int t = threadIdx.x;
    if (t < RR) h[t] = 0;
    __syncthreads();
    int i = blockIdx.x * blockDim.x + t;
    int r = 0, pos = 0;
    if (i < E) { r = et[i]; pos = atomicAdd(&h[r], 1); }
    __syncthreads();
    if (t < RR) base[t] = atomicAdd(&cursor[t], h[t]);
    __syncthreads();
    if (i < E) perm[base[r] + pos] = i;
}

// ---------------- tile FMA helpers ----------------
__device__ __forceinline__ void fma4x4(float c[4][4], const float4 a, const float4 b) {
    c[0][0]=fmaf(a.x,b.x,c[0][0]); c[0][1]=fmaf(a.x,b.y,c[0][1]); c[0][2]=fmaf(a.x,b.z,c[0][2]); c[0][3]=fmaf(a.x,b.w,c[0][3]);
    c[1][0]=fmaf(a.y,b.x,c[1][0]); c[1][1]=fmaf(a.y,b.y,c[1][1]); c[1][2]=fmaf(a.y,b.z,c[1][2]); c[1][3]=fmaf(a.y,b.w,c[1][3]);
    c[2][0]=fmaf(a.z,b.x,c[2][0]); c[2][1]=fmaf(a.z,b.y,c[2][1]); c[2][2]=fmaf(a.z,b.z,c[2][2]); c[2][3]=fmaf(a.z,b.w,c[2][3]);
    c[3][0]=fmaf(a.w,b.x,c[3][0]); c[3][1]=fmaf(a.w,b.y,c[3][1]); c[3][2]=fmaf(a.w,b.z,c[3][2]); c[3][3]=fmaf(a.w,b.w,c[3][3]);
}

__device__ __forceinline__ void fma4x8(float c[4][8], const float4 a, const float4 b0, const float4 b1) {
    c[0][0]=fmaf(a.x,b0.x,c[0][0]); c[0][1]=fmaf(a.x,b0.y,c[0][1]); c[0][2]=fmaf(a.x,b0.z,c[0][2]); c[0][3]=fmaf(a.x,b0.w,c[0][3]);
    c[1][0]=fmaf(a.y,b0.x,c[1][0]); c[1][1]=fmaf(a.y,b0.y,c[1][1]); c[1][2]=fmaf(a.y,b0.z,c[1][2]); c[1][3]=fmaf(a.y,b0.w,c[1][3]);
    c[2][0]=fmaf(a.z,b0.x,c[2][0]); c[2][1]=fmaf(a.z,b0.y,c[2][1]); c[2][2]=fmaf(a.z,b0.z,c[2][2]); c[2][3]=fmaf(a.z,b0.w,c[2][3]);
    c[3][0]=fmaf(a.w,b0.x,c[3][0]); c[3][1]=fmaf(a.w,b0.y,c[3][1]); c[3][2]=fmaf(a.w,b0.z,c[3][2]); c[3][3]=fmaf(a.w,b0.w,c[3][3]);
    c[0][4]=fmaf(a.x,b1.x,c[0][4]); c[0][5]=fmaf(a.x,b1.y,c[0][5]); c[0][6]=fmaf(a.x,b1.z,c[0][6]); c[0][7]=fmaf(a.x,b1.w,c[0][7]);
    c[1][4]=fmaf(a.y,b1.x,c[1][4]); c[1][5]=fmaf(a.y,b1.y,c[1][5]); c[1][6]=fmaf(a.y,b1.z,c[1][6]); c[1][7]=fmaf(a.y,b1.w,c[1][7]);
    c[2][4]=fmaf(a.z,b1.x,c[2][4]); c[2][5]=fmaf(a.z,b1.y,c[2][5]); c[2][6]=fmaf(a.z,b1.z,c[2][6]); c[2][7]=fmaf(a.z,b1.w,c[2][7]);
    c[3][4]=fmaf(a.w,b1.x,c[3][4]); c[3][5]=fmaf(a.w,b1.y,c[3][5]); c[3][6]=fmaf(a.w,b1.z,c[3][6]); c[3][7]=fmaf(a.w,b1.w,c[3][7]);
}

// ---------------- edge message pipeline ----------------
// Per block: 64 edges of one relation r.
//   h1 = relu(X @ W1 + b1)      [64 x 64], K=128
//   h2 = relu(h1 @ W2 + b2)     [64 x 64], K=64
//   msg = relu(h2 @ W3 + b3)    [64 x 128], K=64
//   contrib = msg @ Wn1_slice_r [64 x 64], K=128 -> atomicAdd into acc1[dst]
// LDS (64KB exactly, overlaid):
//   Xs  [0..8192)     X [k=128][m=64]        (dead after GEMM1)
//   Ws  [8192..12288) weight chunk (4096 f)
//   H1  [12288..16384) h1^T [k=64][m=64]     (dead after GEMM2)
//   H2  [0..4096)     h2^T (overlays Xs lo)
//   MsA [4096..8192)  msg^T d in [0,64)  (overlays Xs hi)
//   MsB [12288..16384) msg^T d in [64,128) (overlays H1)
__global__ __launch_bounds__(NT) void k_edge(
    const float* __restrict__ nf, const int* __restrict__ es, const int* __restrict__ ed,
    const float* __restrict__ Wr1, const float* __restrict__ br1,
    const float* __restrict__ Wr2, const float* __restrict__ br2,
    const float* __restrict__ Wr3, const float* __restrict__ br3,
    const float* __restrict__ Wn1,
    const int* __restrict__ perm, const int* __restrict__ segStart, const int* __restrict__ cnt,
    float* __restrict__ acc1)
{
    __shared__ __align__(16) float smem[16384];
    float* Xs  = smem;
    float* Ws  = smem + 8192;
    float* H1  = smem + 12288;
    float* H2  = smem;
    float* MsA = smem + 4096;
    float* MsB = smem + 12288;

    const int r    = blockIdx.y;
    const int len  = cnt[r];
    const int tile = blockIdx.x;
    if (tile * BM >= len) return;
    const int base   = segStart[r] + tile * BM;
    const int mcount = min(BM, len - tile * BM);
    const int tid = threadIdx.x;
    const int tx = tid & 15, ty = tid >> 4;   // n0 = 4*tx (or 8*tx), m0 = 4*ty

    // ---- gather X^T into LDS: wave w loads k in [32w,32w+32), lane = m (conflict-free writes)
    {
        const int w = tid >> 6;
        const int m = tid & 63;
        int gid = -1;
        if (m < mcount) gid = perm[base + m];
        const int srcn = (gid >= 0) ? es[gid] : 0;
        const float4* rowp = (const float4*)(nf + (size_t)srcn * DD) + 8 * w;
        #pragma unroll
        for (int j = 0; j < 8; j++) {
            float4 v = rowp[j];
            if (gid < 0) { v.x = 0.f; v.y = 0.f; v.z = 0.f; v.w = 0.f; }
            const int k = 32 * w + 4 * j;
            Xs[(k+0)*BM + m] = v.x;
            Xs[(k+1)*BM + m] = v.y;
            Xs[(k+2)*BM + m] = v.z;
            Xs[(k+3)*BM + m] = v.w;
        }
    }

    // ---- GEMM1: K=128 in two 64-row weight chunks
    float c1[4][4] = {};
    {
        const float* W1 = Wr1 + (size_t)r * DD * HH;
        for (int kc = 0; kc < 2; kc++) {
            __syncthreads();
            {
                const float4* g = (const float4*)(W1 + kc * 64 * HH);
                float4* s = (float4*)Ws;
                #pragma unroll
                for (int i = 0; i < 4; i++) s[tid + i * NT] = g[tid + i * NT];
            }
            __syncthreads();
            #pragma unroll 8
            for (int kk = 0; kk < 64; kk++) {
                const int k = kc * 64 + kk;
                float4 a = *(const float4*)&Xs[k * BM + 4 * ty];
                float4 b = *(const float4*)&Ws[kk * HH + 4 * tx];
                fma4x4(c1, a, b);
            }
        }
        #pragma unroll
        for (int j = 0; j < 4; j++) {
            const float bv = br1[r * HH + 4 * tx + j];
            #pragma unroll
            for (int i = 0; i < 4; i++) {
                float v = c1[i][j] + bv;
                H1[(4*tx + j) * BM + 4*ty + i] = fmaxf(v, 0.f);
            }
        }
    }

    // ---- GEMM2: K=64, one chunk
    float c2[4][4] = {};
    {
        const float* W2 = Wr2 + (size_t)r * HH * HH;
        __syncthreads();
        {
            const float4* g = (const float4*)W2;
            float4* s = (float4*)Ws;
            #pragma unroll
            for (int i = 0; i < 4; i++) s[tid + i * NT] = g[tid + i * NT];
        }
        __syncthreads();
        #pragma unroll 8
        for (int k = 0; k < 64; k++) {
            float4 a = *(const float4*)&H1[k * BM + 4 * ty];
            float4 b = *(const float4*)&Ws[k * HH + 4 * tx];
            fma4x4(c2, a, b);
        }
        #pragma unroll
        for (int j = 0; j < 4; j++) {
            const float bv = br2[r * HH + 4 * tx + j];
            #pragma unroll
            for (int i = 0; i < 4; i++) {
                float v = c2[i][j] + bv;
                H2[(4*tx + j) * BM + 4*ty + i] = fmaxf(v, 0.f);
            }
        }
    }

    // ---- GEMM3: K=64, N=128, two 32-row weight chunks; 4m x 8n per thread
    float c3[4][8] = {};
    {
        const float* W3 = Wr3 + (size_t)r * HH * DD;
        for (int kc = 0; kc < 2; kc++) {
            __syncthreads();
            {
                const float4* g = (const float4*)(W3 + kc * 32 * DD);
                float4* s = (float4*)Ws;
                #pragma unroll
                for (int i = 0; i < 4; i++) s[tid + i * NT] = g[tid + i * NT];
            }
            __syncthreads();
            #pragma unroll 8
            for (int kk = 0; kk < 32; kk++) {
                const int k = kc * 32 + kk;
                float4 a  = *(const float4*)&H2[k * BM + 4 * ty];
                float4 b0 = *(const float4*)&Ws[kk * DD + 8 * tx];
                float4 b1 = *(const float4*)&Ws[kk * DD + 8 * tx + 4];
                fma4x8(c3, a, b0, b1);
            }
        }
        #pragma unroll
        for (int j = 0; j < 8; j++) {
            const int d = 8 * tx + j;
            const float bv = br3[r * DD + d];
            float* Msp = (d < 64) ? (MsA + d * BM) : (MsB + (d - 64) * BM);
            #pragma unroll
            for (int i = 0; i < 4; i++) {
                float v = c3[i][j] + bv;
                Msp[4*ty + i] = fmaxf(v, 0.f);
            }
        }
    }

    // ---- PROJ: contrib = msg @ Wn1_slice_r, K=128 in two chunks (MsA then MsB)
    float c4[4][4] = {};
    {
        const float* Wp = Wn1 + (size_t)(1 + r) * DD * HH;
        for (int kc = 0; kc < 2; kc++) {
            __syncthreads();
            {
                const float4* g = (const float4*)(Wp + kc * 64 * HH);
                float4* s = (float4*)Ws;
                #pragma unroll
                for (int i = 0; i < 4; i++) s[tid + i * NT] = g[tid + i * NT];
            }
            __syncthreads();
            const float* Msrc = (kc == 0) ? MsA : MsB;
            #pragma unroll 8
            for (int kk = 0; kk < 64; kk++) {
                float4 a = *(const float4*)&Msrc[kk * BM + 4 * ty];
                float4 b = *(const float4*)&Ws[kk * HH + 4 * tx];
                fma4x4(c4, a, b);
            }
        }
        #pragma unroll
        for (int i = 0; i < 4; i++) {
            const int m = 4 * ty + i;
            if (m < mcount) {
                const int gid = perm[base + m];
                const int dn = ed[gid];
                float* ap = acc1 + (size_t)dn * HH + 4 * tx;
                atomicAdd(ap + 0, c4[i][0]);
                atomicAdd(ap + 1, c4[i][1]);
                atomicAdd(ap + 2, c4[i][2]);
                atomicAdd(ap + 3, c4[i][3]);
            }
        }
    }
}

// ---------------- node updater MLP ----------------
__global__ __launch_bounds__(NT) void k_node(
    const float* __restrict__ nf,
    const float* __restrict__ Wn1, const float* __restrict__ bn1,
    const float* __restrict__ Wn2, const float* __restrict__ bn2,
    const float* __restrict__ Wn3, const float* __restrict__ bn3,
    const float* __restrict__ acc1,
    float* __restrict__ out, int Nn)
{
    __shared__ __align__(16) float smem[16384];
    float* Xs = smem;
    float* Ws = smem + 8192;
    float* H1 = smem + 12288;
    float* H2 = smem;

    const int tile = blockIdx.x;
    const int nb0 = tile * BM;
    const int mcount = min(BM, Nn - nb0);
    const int tid = threadIdx.x;
    const int tx = tid & 15, ty = tid >> 4;

    // load relu(node_feature)^T
    {
        const int w = tid >> 6;
        const int m = tid & 63;
        const int node = nb0 + ((m < mcount) ? m : 0);
        const float4* rowp = (const float4*)(nf + (size_t)node * DD) + 8 * w;
        #pragma unroll
        for (int j = 0; j < 8; j++) {
            float4 v = rowp[j];
            const int k = 32 * w + 4 * j;
            Xs[(k+0)*BM + m] = fmaxf(v.x, 0.f);
            Xs[(k+1)*BM + m] = fmaxf(v.y, 0.f);
            Xs[(k+2)*BM + m] = fmaxf(v.z, 0.f);
            Xs[(k+3)*BM + m] = fmaxf(v.w, 0.f);
        }
    }

    // GEMM1n: relu(X @ Wn1[0:128] + acc1 + bn1)
    float c1[4][4] = {};
    {
        for (int kc = 0; kc < 2; kc++) {
            __syncthreads();
            {
                const float4* g = (const float4*)(Wn1 + kc * 64 * HH);
                float4* s = (float4*)Ws;
                #pragma unroll
                for (int i = 0; i < 4; i++) s[tid + i * NT] = g[tid + i * NT];
            }
            __syncthreads();
            #pragma unroll 8
            for (int kk = 0; kk < 64; kk++) {
                const int k = kc * 64 + kk;
                float4 a = *(const float4*)&Xs[k * BM + 4 * ty];
                float4 b = *(const float4*)&Ws[kk * HH + 4 * tx];
                fma4x4(c1, a, b);
            }
        }
        float av[4][4];
        #pragma unroll
        for (int i = 0; i < 4; i++) {
            const int m = 4 * ty + i;
            const int node = nb0 + ((m < mcount) ? m : 0);
            float4 t = *(const float4*)&acc1[(size_t)node * HH + 4 * tx];
            av[i][0] = t.x; av[i][1] = t.y; av[i][2] = t.z; av[i][3] = t.w;
        }
        #pragma unroll
        for (int j = 0; j < 4; j++) {
            const float bv = bn1[4 * tx + j];
            #pragma unroll
            for (int i = 0; i < 4; i++) {
                float v = c1[i][j] + av[i][j] + bv;
                H1[(4*tx + j) * BM + 4*ty + i] = fmaxf(v, 0.f);
            }
        }
    }

    // GEMM2n
    float c2[4][4] = {};
    {
        __syncthreads();
        {
            const float4* g = (const float4*)Wn2;
            float4* s = (float4*)Ws;
            #pragma unroll
            for (int i = 0; i < 4; i++) s[tid + i * NT] = g[tid + i * NT];
        }
        __syncthreads();
        #pragma unroll 8
        for (int k = 0; k < 64; k++) {
            float4 a = *(const float4*)&H1[k * BM + 4 * ty];
            float4 b = *(const float4*)&Ws[k * HH + 4 * tx];
            fma4x4(c2, a, b);
        }
        #pragma unroll
        for (int j = 0; j < 4; j++) {
            const float bv = bn2[4 * tx + j];
            #pragma unroll
            for (int i = 0; i < 4; i++) {
                float v = c2[i][j] + bv;
                H2[(4*tx + j) * BM + 4*ty + i] = fmaxf(v, 0.f);
            }
        }
    }

    // GEMM3n: K=64, N=128 -> out (+bn3, no relu)
    float c3[4][8] = {};
    {
        for (int kc = 0; kc < 2; kc++) {
            __syncthreads();
            {
                const float4* g = (const float4*)(Wn3 + kc * 32 * DD);
                float4* s = (float4*)Ws;
                #pragma unroll
                for (int i = 0; i < 4; i++) s[tid + i * NT] = g[tid + i * NT];
            }
            __syncthreads();
            #pragma unroll 8
            for (int kk = 0; kk < 32; kk++) {
                const int k = kc * 32 + kk;
                float4 a  = *(const float4*)&H2[k * BM + 4 * ty];
                float4 b0 = *(const float4*)&Ws[kk * DD + 8 * tx];
                float4 b1 = *(const float4*)&Ws[kk * DD + 8 * tx + 4];
                fma4x8(c3, a, b0, b1);
            }
        }
        float bL[8];
        #pragma unroll
        for (int j = 0; j < 8; j++) bL[j] = bn3[8 * tx + j];
        #pragma unroll
        for (int i = 0; i < 4; i++) {
            const int m = 4 * ty + i;
            if (m < mcount) {
                const size_t o = (size_t)(nb0 + m) * DD + 8 * tx;
                float4 o0, o1;
                o0.x = c3[i][0] + bL[0]; o0.y = c3[i][1] + bL[1];
                o0.z = c3[i][2] + bL[2]; o0.w = c3[i][3] + bL[3];
                o1.x = c3[i][4] + bL[4]; o1.y = c3[i][5] + bL[5];
                o1.z = c3[i][6] + bL[6]; o1.w = c3[i][7] + bL[7];
                *(float4*)&out[o]     = o0;
                *(float4*)&out[o + 4] = o1;
            }
        }
    }
}

extern "C" void kernel_launch(void* const* d_in, const int* in_sizes, int n_in,
                              void* d_out, int out_size, void* d_ws, size_t ws_size,
                              hipStream_t stream) {
    const float* nf  = (const float*)d_in[0];
    const int*   es  = (const int*)d_in[1];
    const int*   ed  = (const int*)d_in[2];
    const int*   et  = (const int*)d_in[3];
    const float* Wr1 = (const float*)d_in[4];
    const float* br1 = (const float*)d_in[5];
    const float* Wr2 = (const float*)d_in[6];
    const float* br2 = (const float*)d_in[7];
    const float* Wr3 = (const float*)d_in[8];
    const float* br3 = (const float*)d_in[9];
    const float* Wn1 = (const float*)d_in[10];
    const float* bn1 = (const float*)d_in[11];
    const float* Wn2 = (const float*)d_in[12];
    const float* bn2 = (const float*)d_in[13];
    const float* Wn3 = (const float*)d_in[14];
    const float* bn3 = (const float*)d_in[15];
    float* out = (float*)d_out;

    const int Nn = in_sizes[0] / DD;   // 50000
    const int E  = in_sizes[1];        // 200000

    float* acc1   = (float*)d_ws;                       // Nn*HH floats (pre-activation accumulator)
    int*   perm   = (int*)(acc1 + (size_t)Nn * HH);     // E
    int*   cnt    = perm + E;                           // RR
    int*   segSt  = cnt + RR;                           // RR
    int*   cursor = segSt + RR;                         // RR

    const size_t zbytes = ((size_t)Nn * HH + (size_t)E + 3 * RR) * sizeof(float);
    hipMemsetAsync(d_ws, 0, zbytes, stream);

    const int nb = (E + NT - 1) / NT;
    k_count  <<<nb, NT, 0, stream>>>(et, cnt, E);
    k_scan   <<<1, 64, 0, stream>>>(cnt, segSt, cursor);
    k_scatter<<<nb, NT, 0, stream>>>(et, cursor, perm, E);

    dim3 ge((E + BM - 1) / BM, RR);
    k_edge<<<ge, NT, 0, stream>>>(nf, es, ed, Wr1, br1, Wr2, br2, Wr3, br3, Wn1,
                                  perm, segSt, cnt, acc1);
    k_node<<<(Nn + BM - 1) / BM, NT, 0, stream>>>(nf, Wn1, bn1, Wn2, bn2, Wn3, bn3,
                                                  acc1, out, Nn);
}

// Round 2
// 260.574 us; speedup vs baseline: 1.5988x; 1.5988x over previous
//
#include <hip/hip_runtime.h>

#define DD 128
#define HH 64
#define RR 4
#define BM 64
#define NT 256

typedef __attribute__((ext_vector_type(8))) __bf16 bf16x8;
typedef __attribute__((ext_vector_type(4))) float f32x4;

// LDS row strides (bf16 elements); rows stay 16B-aligned, +8 pad rotates banks
#define LXS 136   // X / Msg rows (K=128 + 8)
#define LHS 72    // H1/H2 rows  (K=64 + 8)
// smem element offsets
#define OXS 0
#define OH1 8704
#define OH2 13312
#define SMEM_ELEMS 17920   // 35840 B -> 4 blocks/CU

// transposed bf16 weight pool offsets (elements)
#define W1T_OFF 0        // [R][64][128]
#define W2T_OFF 32768    // [R][64][64]
#define W3T_OFF 49152    // [R][128][64]
#define WPT_OFF 81920    // [R][64][128]  (Wn1 slice 1+r)
#define WN1_OFF 114688   // [64][128]     (Wn1 slice 0)
#define WN2_OFF 122880   // [64][64]
#define WN3_OFF 126976   // [128][64]
#define WT_TOTAL 135168

// ---------------- relation counting sort ----------------
__global__ void k_count(const int* __restrict__ et, int* __restrict__ cnt, int E) {
    __shared__ int h[RR];
    int t = threadIdx.x;
    if (t < RR) h[t] = 0;
    __syncthreads();
    int i = blockIdx.x * blockDim.x + t;
    if (i < E) atomicAdd(&h[et[i]], 1);
    __syncthreads();
    if (t < RR) atomicAdd(&cnt[t], h[t]);
}

__global__ void k_scan(const int* __restrict__ cnt, int* __restrict__ segStart,
                       int* __restrict__ cursor) {
    if (threadIdx.x == 0 && blockIdx.x == 0) {
        int s = 0;
        for (int r = 0; r < RR; r++) { segStart[r] = s; cursor[r] = s; s += cnt[r]; }
    }
}

__global__ void k_scatter(const int* __restrict__ et, int* __restrict__ cursor,
                          int* __restrict__ perm, int E) {
    __shared__ int h[RR];
    __shared__ int base[RR];
    int t = threadIdx.x;
    if (t < RR) h[t] = 0;
    __syncthreads();
    int i = blockIdx.x * blockDim.x + t;
    int r = 0, pos = 0;
    if (i < E) { r = et[i]; pos = atomicAdd(&h[r], 1); }
    __syncthreads();
    if (t < RR) base[t] = atomicAdd(&cursor[t], h[t]);
    __syncthreads();
    if (i < E) perm[base[r] + pos] = i;
}

// ---------------- weight transpose+convert (once per launch) ----------------
__global__ void k_prep(const float* __restrict__ Wr1, const float* __restrict__ Wr2,
                       const float* __restrict__ Wr3, const float* __restrict__ Wn1,
                       const float* __restrict__ Wn2, const float* __restrict__ Wn3,
                       __bf16* __restrict__ wt) {
    int i = blockIdx.x * blockDim.x + threadIdx.x;
    float v;
    if (i < 32768) {                       // W1t [r][n64][k128]
        int r = i >> 13, n = (i >> 7) & 63, k = i & 127;
        v = Wr1[r * 8192 + k * 64 + n];
    } else if (i < 49152) {                // W2t [r][n64][k64]
        int j = i - 32768; int r = j >> 12, n = (j >> 6) & 63, k = j & 63;
        v = Wr2[r * 4096 + k * 64 + n];
    } else if (i < 81920) {                // W3t [r][n128][k64]
        int j = i - 49152; int r = j >> 13, n = (j >> 6) & 127, k = j & 63;
        v = Wr3[r * 8192 + k * 128 + n];
    } else if (i < 114688) {               // Wpt [r][n64][k128]
        int j = i - 81920; int r = j >> 13, n = (j >> 7) & 63, k = j & 127;
        v = Wn1[((1 + r) * 128 + k) * 64 + n];
    } else if (i < 122880) {               // Wn1t0 [n64][k128]
        int j = i - 114688; int n = j >> 7, k = j & 127;
        v = Wn1[k * 64 + n];
    } else if (i < 126976) {               // Wn2t [n64][k64]
        int j = i - 122880; int n = j >> 6, k = j & 63;
        v = Wn2[k * 64 + n];
    } else if (i < WT_TOTAL) {             // Wn3t [n128][k64]
        int j = i - 126976; int n = j >> 6, k = j & 63;
        v = Wn3[k * 128 + n];
    } else return;
    wt[i] = (__bf16)v;
}

// ---------------- edge message pipeline (MFMA, barrier-free) ----------------
__global__ __launch_bounds__(NT, 4) void k_edge(
    const float* __restrict__ nf, const int* __restrict__ es, const int* __restrict__ ed,
    const float* __restrict__ br1, const float* __restrict__ br2, const float* __restrict__ br3,
    const __bf16* __restrict__ wt,
    const int* __restrict__ perm, const int* __restrict__ segStart, const int* __restrict__ cnt,
    float* __restrict__ accn)
{
    __shared__ __bf16 smem[SMEM_ELEMS];
    __bf16* Xs = smem + OXS;   // [64][LXS]
    __bf16* H1 = smem + OH1;   // [64][LHS]
    __bf16* H2 = smem + OH2;   // [64][LHS]
    __bf16* Ms = smem + OXS;   // [64][LXS] overlays Xs (dead after GEMM1)

    const int r = blockIdx.y;
    const int len = cnt[r];
    const int tile = blockIdx.x;
    if (tile * BM >= len) return;
    const int base = segStart[r] + tile * BM;
    const int mcount = min(BM, len - tile * BM);
    const int tid = threadIdx.x;
    const int w = tid >> 6;
    const int lane = tid & 63;
    const int ln = lane & 15, qd = lane >> 4;
    const int m0 = w << 4;     // wave-owned m-tile: rows m0..m0+15

    // ---- stage X rows (wave-local: thread t handles row t>>2 in its own tile)
    {
        const int m = tid >> 2, q = tid & 3;
        int srcn = 0;
        if (m < mcount) srcn = es[perm[base + m]];
        const float4* rp = (const float4*)(nf + (size_t)srcn * DD) + 8 * q;
        __bf16* xr = Xs + m * LXS + 32 * q;
        #pragma unroll
        for (int jj = 0; jj < 4; jj++) {
            float4 v0 = rp[2 * jj], v1 = rp[2 * jj + 1];
            bf16x8 p;
            p[0] = (__bf16)v0.x; p[1] = (__bf16)v0.y; p[2] = (__bf16)v0.z; p[3] = (__bf16)v0.w;
            p[4] = (__bf16)v1.x; p[5] = (__bf16)v1.y; p[6] = (__bf16)v1.z; p[7] = (__bf16)v1.w;
            *(bf16x8*)(xr + 8 * jj) = p;
        }
    }

    // ---- GEMM1: h1 = relu(X @ W1 + b1)   M64 N64 K128
    {
        const __bf16* W1t = wt + W1T_OFF + r * 8192;
        f32x4 c[4] = {};
        #pragma unroll
        for (int ks = 0; ks < 128; ks += 32) {
            bf16x8 a = *(const bf16x8*)(Xs + (m0 + ln) * LXS + ks + 8 * qd);
            #pragma unroll
            for (int nt = 0; nt < 4; nt++) {
                bf16x8 b = *(const bf16x8*)(W1t + (nt * 16 + ln) * 128 + ks + 8 * qd);
                c[nt] = __builtin_amdgcn_mfma_f32_16x16x32_bf16(a, b, c[nt], 0, 0, 0);
            }
        }
        #pragma unroll
        for (int nt = 0; nt < 4; nt++) {
            float bv = br1[r * HH + nt * 16 + ln];
            #pragma unroll
            for (int rg = 0; rg < 4; rg++) {
                float v = c[nt][rg] + bv;
                H1[(m0 + qd * 4 + rg) * LHS + nt * 16 + ln] = (__bf16)fmaxf(v, 0.f);
            }
        }
    }

    // ---- GEMM2: h2 = relu(h1 @ W2 + b2)  M64 N64 K64
    {
        const __bf16* W2t = wt + W2T_OFF + r * 4096;
        f32x4 c[4] = {};
        #pragma unroll
        for (int ks = 0; ks < 64; ks += 32) {
            bf16x8 a = *(const bf16x8*)(H1 + (m0 + ln) * LHS + ks + 8 * qd);
            #pragma unroll
            for (int nt = 0; nt < 4; nt++) {
                bf16x8 b = *(const bf16x8*)(W2t + (nt * 16 + ln) * 64 + ks + 8 * qd);
                c[nt] = __builtin_amdgcn_mfma_f32_16x16x32_bf16(a, b, c[nt], 0, 0, 0);
            }
        }
        #pragma unroll
        for (int nt = 0; nt < 4; nt++) {
            float bv = br2[r * HH + nt * 16 + ln];
            #pragma unroll
            for (int rg = 0; rg < 4; rg++) {
                float v = c[nt][rg] + bv;
                H2[(m0 + qd * 4 + rg) * LHS + nt * 16 + ln] = (__bf16)fmaxf(v, 0.f);
            }
        }
    }

    // ---- GEMM3: msg = relu(h2 @ W3 + b3)  M64 N128 K64
    {
        const __bf16* W3t = wt + W3T_OFF + r * 8192;
        f32x4 c[8] = {};
        #pragma unroll
        for (int ks = 0; ks < 64; ks += 32) {
            bf16x8 a = *(const bf16x8*)(H2 + (m0 + ln) * LHS + ks + 8 * qd);
            #pragma unroll
            for (int nt = 0; nt < 8; nt++) {
                bf16x8 b = *(const bf16x8*)(W3t + (nt * 16 + ln) * 64 + ks + 8 * qd);
                c[nt] = __builtin_amdgcn_mfma_f32_16x16x32_bf16(a, b, c[nt], 0, 0, 0);
            }
        }
        #pragma unroll
        for (int nt = 0; nt < 8; nt++) {
            float bv = br3[r * DD + nt * 16 + ln];
            #pragma unroll
            for (int rg = 0; rg < 4; rg++) {
                float v = c[nt][rg] + bv;
                Ms[(m0 + qd * 4 + rg) * LXS + nt * 16 + ln] = (__bf16)fmaxf(v, 0.f);
            }
        }
    }

    // ---- PROJ: contrib = msg @ Wn1_slice(1+r)  M64 N64 K128 -> fp32 atomics
    {
        const __bf16* Wpt = wt + WPT_OFF + r * 8192;
        f32x4 c[4] = {};
        #pragma unroll
        for (int ks = 0; ks < 128; ks += 32) {
            bf16x8 a = *(const bf16x8*)(Ms + (m0 + ln) * LXS + ks + 8 * qd);
            #pragma unroll
            for (int nt = 0; nt < 4; nt++) {
                bf16x8 b = *(const bf16x8*)(Wpt + (nt * 16 + ln) * 128 + ks + 8 * qd);
                c[nt] = __builtin_amdgcn_mfma_f32_16x16x32_bf16(a, b, c[nt], 0, 0, 0);
            }
        }
        #pragma unroll
        for (int rg = 0; rg < 4; rg++) {
            const int m = m0 + qd * 4 + rg;
            if (m < mcount) {
                const int dn = ed[perm[base + m]];
                float* ap = accn + (size_t)dn * HH;
                #pragma unroll
                for (int nt = 0; nt < 4; nt++)
                    atomicAdd(ap + nt * 16 + ln, c[nt][rg]);
            }
        }
    }
}

// ---------------- node updater MLP (MFMA, barrier-free) ----------------
__global__ __launch_bounds__(NT, 4) void k_node(
    const float* __restrict__ nf,
    const float* __restrict__ bn1, const float* __restrict__ bn2, const float* __restrict__ bn3,
    const __bf16* __restrict__ wt, const float* __restrict__ accn,
    float* __restrict__ out, int Nn)
{
    __shared__ __bf16 smem[SMEM_ELEMS];
    __bf16* Xs = smem + OXS;
    __bf16* H1 = smem + OH1;
    __bf16* H2 = smem + OH2;

    const int nb0 = blockIdx.x * BM;
    const int mcount = min(BM, Nn - nb0);
    const int tid = threadIdx.x;
    const int w = tid >> 6;
    const int lane = tid & 63;
    const int ln = lane & 15, qd = lane >> 4;
    const int m0 = w << 4;

    // stage relu(node_feature) rows (wave-local)
    {
        const int m = tid >> 2, q = tid & 3;
        const int node = nb0 + ((m < mcount) ? m : 0);
        const float4* rp = (const float4*)(nf + (size_t)node * DD) + 8 * q;
        __bf16* xr = Xs + m * LXS + 32 * q;
        #pragma unroll
        for (int jj = 0; jj < 4; jj++) {
            float4 v0 = rp[2 * jj], v1 = rp[2 * jj + 1];
            bf16x8 p;
            p[0] = (__bf16)fmaxf(v0.x, 0.f); p[1] = (__bf16)fmaxf(v0.y, 0.f);
            p[2] = (__bf16)fmaxf(v0.z, 0.f); p[3] = (__bf16)fmaxf(v0.w, 0.f);
            p[4] = (__bf16)fmaxf(v1.x, 0.f); p[5] = (__bf16)fmaxf(v1.y, 0.f);
            p[6] = (__bf16)fmaxf(v1.z, 0.f); p[7] = (__bf16)fmaxf(v1.w, 0.f);
            *(bf16x8*)(xr + 8 * jj) = p;
        }
    }

    // GEMM1n: h = relu(relu(X) @ Wn1_0 + accn + bn1)  K128 N64
    {
        const __bf16* Wt = wt + WN1_OFF;
        f32x4 c[4] = {};
        #pragma unroll
        for (int ks = 0; ks < 128; ks += 32) {
            bf16x8 a = *(const bf16x8*)(Xs + (m0 + ln) * LXS + ks + 8 * qd);
            #pragma unroll
            for (int nt = 0; nt < 4; nt++) {
                bf16x8 b = *(const bf16x8*)(Wt + (nt * 16 + ln) * 128 + ks + 8 * qd);
                c[nt] = __builtin_amdgcn_mfma_f32_16x16x32_bf16(a, b, c[nt], 0, 0, 0);
            }
        }
        #pragma unroll
        for (int nt = 0; nt < 4; nt++) {
            float bv = bn1[nt * 16 + ln];
            #pragma unroll
            for (int rg = 0; rg < 4; rg++) {
                const int m = m0 + qd * 4 + rg;
                const int node = nb0 + ((m < mcount) ? m : 0);
                float v = c[nt][rg] + bv + accn[(size_t)node * HH + nt * 16 + ln];
                H1[m * LHS + nt * 16 + ln] = (__bf16)fmaxf(v, 0.f);
            }
        }
    }

    // GEMM2n: K64 N64
    {
        const __bf16* Wt = wt + WN2_OFF;
        f32x4 c[4] = {};
        #pragma unroll
        for (int ks = 0; ks < 64; ks += 32) {
            bf16x8 a = *(const bf16x8*)(H1 + (m0 + ln) * LHS + ks + 8 * qd);
            #pragma unroll
            for (int nt = 0; nt < 4; nt++) {
                bf16x8 b = *(const bf16x8*)(Wt + (nt * 16 + ln) * 64 + ks + 8 * qd);
                c[nt] = __builtin_amdgcn_mfma_f32_16x16x32_bf16(a, b, c[nt], 0, 0, 0);
            }
        }
        #pragma unroll
        for (int nt = 0; nt < 4; nt++) {
            float bv = bn2[nt * 16 + ln];
            #pragma unroll
            for (int rg = 0; rg < 4; rg++) {
                float v = c[nt][rg] + bv;
                H2[(m0 + qd * 4 + rg) * LHS + nt * 16 + ln] = (__bf16)fmaxf(v, 0.f);
            }
        }
    }

    // GEMM3n: K64 N128 -> out (+bn3, no relu)
    {
        const __bf16* Wt = wt + WN3_OFF;
        f32x4 c[8] = {};
        #pragma unroll
        for (int ks = 0; ks < 64; ks += 32) {
            bf16x8 a = *(const bf16x8*)(H2 + (m0 + ln) * LHS + ks + 8 * qd);
            #pragma unroll
            for (int nt = 0; nt < 8; nt++) {
                bf16x8 b = *(const bf16x8*)(Wt + (nt * 16 + ln) * 64 + ks + 8 * qd);
                c[nt] = __builtin_amdgcn_mfma_f32_16x16x32_bf16(a, b, c[nt], 0, 0, 0);
            }
        }
        #pragma unroll
        for (int rg = 0; rg < 4; rg++) {
            const int m = m0 + qd * 4 + rg;
            if (m < mcount) {
                float* op = out + (size_t)(nb0 + m) * DD;
                #pragma unroll
                for (int nt = 0; nt < 8; nt++)
                    op[nt * 16 + ln] = c[nt][rg] + bn3[nt * 16 + ln];
            }
        }
    }
}

extern "C" void kernel_launch(void* const* d_in, const int* in_sizes, int n_in,
                              void* d_out, int out_size, void* d_ws, size_t ws_size,
                              hipStream_t stream) {
    const float* nf  = (const float*)d_in[0];
    const int*   es  = (const int*)d_in[1];
    const int*   ed  = (const int*)d_in[2];
    const int*   et  = (const int*)d_in[3];
    const float* Wr1 = (const float*)d_in[4];
    const float* br1 = (const float*)d_in[5];
    const float* Wr2 = (const float*)d_in[6];
    const float* br2 = (const float*)d_in[7];
    const float* Wr3 = (const float*)d_in[8];
    const float* br3 = (const float*)d_in[9];
    const float* Wn1 = (const float*)d_in[10];
    const float* bn1 = (const float*)d_in[11];
    const float* Wn2 = (const float*)d_in[12];
    const float* bn2 = (const float*)d_in[13];
    const float* Wn3 = (const float*)d_in[14];
    const float* bn3 = (const float*)d_in[15];
    float* out = (float*)d_out;

    const int Nn = in_sizes[0] / DD;   // 50000
    const int E  = in_sizes[1];        // 200000

    float*  accn   = (float*)d_ws;                      // Nn*HH fp32 accumulator
    int*    perm   = (int*)(accn + (size_t)Nn * HH);    // E
    int*    cnt    = perm + E;                          // RR
    int*    segSt  = cnt + RR;                          // RR
    int*    cursor = segSt + RR;                        // RR
    __bf16* wbf    = (__bf16*)(cursor + RR);            // WT_TOTAL bf16 (16B-aligned)

    const size_t zbytes = ((size_t)Nn * HH + (size_t)E + 3 * RR) * sizeof(float);
    hipMemsetAsync(d_ws, 0, zbytes, stream);

    const int nb = (E + NT - 1) / NT;
    k_count  <<<nb, NT, 0, stream>>>(et, cnt, E);
    k_scan   <<<1, 64, 0, stream>>>(cnt, segSt, cursor);
    k_scatter<<<nb, NT, 0, stream>>>(et, cursor, perm, E);
    k_prep   <<<(WT_TOTAL + NT - 1) / NT, NT, 0, stream>>>(Wr1, Wr2, Wr3, Wn1, Wn2, Wn3, wbf);

    dim3 ge((E + BM - 1) / BM, RR);
    k_edge<<<ge, NT, 0, stream>>>(nf, es, ed, br1, br2, br3, wbf, perm, segSt, cnt, accn);
    k_node<<<(Nn + BM - 1) / BM, NT, 0, stream>>>(nf, bn1, bn2, bn3, wbf, accn, out, Nn);
}